// Round 11
// baseline (178.826 us; speedup 1.0000x reference)
//
#include <hip/hip_runtime.h>
#include <hip/hip_bf16.h>

// IG-MSA restructured pipeline. Round 11: ABLATION round.
//   k3t<0>: real kernel (round-10 + PV acc split) -> writes out
//   k3t<1>: staging skeleton only (DMA + vm-barrier + token consume)
//   k3t<2>: + frag build + vgen MFMA + gate (keepalive, no exchange/PV)
//   k3t<3>: full minus global stores (keepalive on ov)
// Modes 1-3 write tokens into the already-consumed xx scratch region.

#define NPOS 65536
#define CH 64
#define INNER 256

typedef __attribute__((ext_vector_type(8))) __bf16 bfrag;
typedef __attribute__((ext_vector_type(4))) float facc;
typedef __attribute__((ext_vector_type(4))) float fvec4;

typedef const __attribute__((address_space(1))) unsigned int guint;
typedef __attribute__((address_space(3))) unsigned int luint;

__device__ __forceinline__ unsigned short f2bu(float f) {
  return __builtin_bit_cast(unsigned short, (__bf16)f);
}

#define SWA(row, colbyte) ((row) * 128 + ((colbyte) ^ (((row) & 7) << 4)))

#define BAR_VM4()  asm volatile("s_waitcnt vmcnt(4)\n\ts_barrier" ::: "memory")
#define BAR_VM0()  asm volatile("s_waitcnt vmcnt(0)\n\ts_barrier" ::: "memory")
#define BAR_LGKM() asm volatile("s_waitcnt lgkmcnt(0)\n\ts_barrier" ::: "memory")
#define KEEP(v)    asm volatile("" :: "v"(v))

// ---------------- K0: weight transpose to bf16 ----------------
__global__ __launch_bounds__(256) void k0_wt(const float* __restrict__ Wv,
                                             const float* __restrict__ WL,
                                             unsigned short* __restrict__ WvT,
                                             unsigned short* __restrict__ WLT) {
  int t = blockIdx.x * 256 + threadIdx.x;
  int c = t >> 8, i = t & 255;
  WvT[i * CH + c] = f2bu(Wv[c * INNER + i]);
  WLT[i * CH + c] = f2bu(WL[c * INNER + i]);
}

// ---------------- K1: channel Gram matrix ----------------
__global__ __launch_bounds__(256) void k1_xx(const float* __restrict__ x,
                                             float* __restrict__ xx) {
  const int b = blockIdx.y;
  const int wave = threadIdx.x >> 6, lane = threadIdx.x & 63;
  const int r = lane & 15, g = lane >> 4;
  const int gw = blockIdx.x * 4 + wave;
  const int per = NPOS / 128;
  const size_t n0 = (size_t)gw * per;
  const float* xb = x + (size_t)b * CH * NPOS;

  facc acc[4][4] = {};

  for (int n = 0; n < per; n += 32) {
    bfrag fr[4];
#pragma unroll
    for (int t = 0; t < 4; ++t) {
      const float* p = xb + (size_t)(16 * t + r) * NPOS + n0 + n + g * 8;
      fvec4 lo = *(const fvec4*)p;
      fvec4 hi = *(const fvec4*)(p + 4);
      bfrag f;
#pragma unroll
      for (int e = 0; e < 4; ++e) { f[e] = (__bf16)lo[e]; f[e + 4] = (__bf16)hi[e]; }
      fr[t] = f;
    }
#pragma unroll
    for (int ti = 0; ti < 4; ++ti)
#pragma unroll
      for (int tj = 0; tj < 4; ++tj)
        acc[ti][tj] = __builtin_amdgcn_mfma_f32_16x16x32_bf16(fr[ti], fr[tj],
                                                              acc[ti][tj], 0, 0, 0);
  }

  __shared__ float red[4][4096];
  float* my = red[wave];
#pragma unroll
  for (int ti = 0; ti < 4; ++ti)
#pragma unroll
    for (int tj = 0; tj < 4; ++tj)
#pragma unroll
      for (int q = 0; q < 4; ++q)
        my[(16 * ti + g * 4 + q) * 64 + 16 * tj + r] = acc[ti][tj][q];
  __syncthreads();
  float* xxb = xx + (size_t)b * 4096;
  for (int i = threadIdx.x; i < 4096; i += 256)
    atomicAdd(xxb + i, red[0][i] + red[1][i] + red[2][i] + red[3][i]);
}

// ---------------- K2: MFMA finalize attention, fold Wp ----------------
__global__ __launch_bounds__(256) void k2_attn(
    const float* __restrict__ xx, const float* __restrict__ Wq,
    const float* __restrict__ Wk, const float* __restrict__ rescale,
    const float* __restrict__ Wp, unsigned short* __restrict__ Mt) {
  const int b = blockIdx.x >> 2, h = blockIdx.x & 3;
  const int t = threadIdx.x;
  const int wave = t >> 6, lane = t & 63;
  const int r = lane & 15, g = lane >> 4;

  __shared__ __align__(16) char tXX[8192];
  __shared__ __align__(16) char tWq[8192];
  __shared__ __align__(16) char tWk[8192];
  __shared__ __align__(16) char tWp[8192];
  __shared__ __align__(16) char tZq[8192];
  __shared__ __align__(16) char tZk[8192];
  __shared__ __align__(16) char tAt[8192];
  __shared__ float gG[64][68];
  __shared__ float sMx[64][4], sSm[64][4];
  __shared__ float sNq[64], sNk[64];

  const float* xxb = xx + (size_t)b * 4096;
#pragma unroll
  for (int rep = 0; rep < 16; ++rep) {
    int idx = rep * 256 + t;
    int row = idx >> 6, col = idx & 63;
    *(unsigned short*)(tXX + SWA(row, col * 2)) = f2bu(xxb[idx]);
    float vq = Wq[row * INNER + h * 64 + col];
    float vk = Wk[row * INNER + h * 64 + col];
    *(unsigned short*)(tWq + SWA(col, row * 2)) = f2bu(vq);
    *(unsigned short*)(tWk + SWA(col, row * 2)) = f2bu(vk);
    *(unsigned short*)(tWp + SWA(col, row * 2)) = f2bu(Wp[(h * 64 + row) * CH + col]);
  }
  __syncthreads();

  facc zq[4] = {}, zk[4] = {};
#pragma unroll
  for (int s = 0; s < 2; ++s) {
    bfrag aq = *(const bfrag*)(tWq + SWA(16 * wave + r, s * 64 + g * 16));
    bfrag ak = *(const bfrag*)(tWk + SWA(16 * wave + r, s * 64 + g * 16));
#pragma unroll
    for (int tj = 0; tj < 4; ++tj) {
      bfrag bx = *(const bfrag*)(tXX + SWA(16 * tj + r, s * 64 + g * 16));
      zq[tj] = __builtin_amdgcn_mfma_f32_16x16x32_bf16(aq, bx, zq[tj], 0, 0, 0);
      zk[tj] = __builtin_amdgcn_mfma_f32_16x16x32_bf16(ak, bx, zk[tj], 0, 0, 0);
    }
  }
#pragma unroll
  for (int tj = 0; tj < 4; ++tj)
#pragma unroll
    for (int q = 0; q < 4; ++q) {
      int row = 16 * wave + g * 4 + q, colb = (16 * tj + r) * 2;
      *(unsigned short*)(tZq + SWA(row, colb)) = f2bu(zq[tj][q]);
      *(unsigned short*)(tZk + SWA(row, colb)) = f2bu(zk[tj][q]);
    }
  __syncthreads();

  facc ga[4] = {}, q2[4] = {}, k2[4] = {};
#pragma unroll
  for (int s = 0; s < 2; ++s) {
    bfrag azk = *(const bfrag*)(tZk + SWA(16 * wave + r, s * 64 + g * 16));
    bfrag azq = *(const bfrag*)(tZq + SWA(16 * wave + r, s * 64 + g * 16));
#pragma unroll
    for (int tj = 0; tj < 4; ++tj) {
      bfrag bq = *(const bfrag*)(tWq + SWA(16 * tj + r, s * 64 + g * 16));
      bfrag bk = *(const bfrag*)(tWk + SWA(16 * tj + r, s * 64 + g * 16));
      ga[tj] = __builtin_amdgcn_mfma_f32_16x16x32_bf16(azk, bq, ga[tj], 0, 0, 0);
      q2[tj] = __builtin_amdgcn_mfma_f32_16x16x32_bf16(azq, bq, q2[tj], 0, 0, 0);
      k2[tj] = __builtin_amdgcn_mfma_f32_16x16x32_bf16(azk, bk, k2[tj], 0, 0, 0);
    }
  }
#pragma unroll
  for (int tj = 0; tj < 4; ++tj)
#pragma unroll
    for (int q = 0; q < 4; ++q) {
      int row = 16 * wave + g * 4 + q, col = 16 * tj + r;
      gG[row][col] = ga[tj][q];
      if (row == col) { sNq[row] = q2[tj][q]; sNk[row] = k2[tj][q]; }
    }
  __syncthreads();

  if (t < 64) {
    sNq[t] = 1.f / fmaxf(sqrtf(sNq[t]), 1e-12f);
    sNk[t] = rescale[h] / fmaxf(sqrtf(sNk[t]), 1e-12f);
  }
  __syncthreads();

  {
    const int d = t >> 2, p = t & 3;
    const float ik = sNk[d];
    float le[16];
    float mx = -1e30f;
#pragma unroll
    for (int j = 0; j < 16; ++j) {
      float v = gG[d][16 * p + j] * ik * sNq[16 * p + j];
      le[j] = v; mx = fmaxf(mx, v);
    }
    sMx[d][p] = mx;
    __syncthreads();
    mx = fmaxf(fmaxf(sMx[d][0], sMx[d][1]), fmaxf(sMx[d][2], sMx[d][3]));
    float sm = 0.f;
#pragma unroll
    for (int j = 0; j < 16; ++j) { le[j] = __expf(le[j] - mx); sm += le[j]; }
    sSm[d][p] = sm;
    __syncthreads();
    sm = sSm[d][0] + sSm[d][1] + sSm[d][2] + sSm[d][3];
    const float inv = 1.f / sm;
#pragma unroll
    for (int j = 0; j < 16; ++j) {
      int e = 16 * p + j;
      *(unsigned short*)(tAt + SWA(e, d * 2)) = f2bu(le[j] * inv);
    }
  }
  __syncthreads();

  facc m[4] = {};
#pragma unroll
  for (int s = 0; s < 2; ++s) {
    bfrag aa = *(const bfrag*)(tAt + SWA(16 * wave + r, s * 64 + g * 16));
#pragma unroll
    for (int tj = 0; tj < 4; ++tj) {
      bfrag bw = *(const bfrag*)(tWp + SWA(16 * tj + r, s * 64 + g * 16));
      m[tj] = __builtin_amdgcn_mfma_f32_16x16x32_bf16(aa, bw, m[tj], 0, 0, 0);
    }
  }
#pragma unroll
  for (int tj = 0; tj < 4; ++tj)
#pragma unroll
    for (int q = 0; q < 4; ++q) {
      int e = 16 * wave + g * 4 + q, c2 = 16 * tj + r;
      Mt[((size_t)(b * CH + c2)) * INNER + h * 64 + e] = f2bu(m[tj][q]);
    }
}

// ---------------- K3 (templated ablation) ----------------
template <int MODE>
__global__ __launch_bounds__(256) void k3t(
    const float* __restrict__ x, const float* __restrict__ illu,
    const unsigned short* __restrict__ WvT, const unsigned short* __restrict__ WLT,
    const unsigned short* __restrict__ Mt, const float* __restrict__ bp,
    float* __restrict__ out, float* __restrict__ tokbuf) {
  const int b = blockIdx.y;
  const int wave = threadIdx.x >> 6, lane = threadIdx.x & 63;
  const int r = lane & 15, g = lane >> 4;
  const int n0 = blockIdx.x * 256;

  __shared__ __align__(16) float xf[2][64][32];
  __shared__ __align__(16) float ifl[2][64][32];
  __shared__ __align__(16) char lvs[2][8192];

  bfrag wvA[4][2], wlA[4][2], mtA[8];
#pragma unroll
  for (int ti = 0; ti < 4; ++ti) {
    const int i = wave * 64 + ti * 16 + r;
#pragma unroll
    for (int s = 0; s < 2; ++s) {
      wvA[ti][s] = *(const bfrag*)(WvT + i * CH + s * 32 + g * 8);
      wlA[ti][s] = *(const bfrag*)(WLT + i * CH + s * 32 + g * 8);
    }
  }
#pragma unroll
  for (int s8 = 0; s8 < 8; ++s8)
    mtA[s8] = *(const bfrag*)(Mt + ((size_t)(b * CH + wave * 16 + r)) * INNER + s8 * 32 + g * 8);
  float bcol[4];
#pragma unroll
  for (int q = 0; q < 4; ++q) bcol[q] = bp[wave * 16 + g * 4 + q];

  const float* xb = x + (size_t)b * CH * NPOS;
  const float* ib = illu + (size_t)b * CH * NPOS;
  float* ob = out + (size_t)b * CH * NPOS;

  const int c0 = wave * 16 + (lane >> 3);
  const int c1 = c0 + 8;
  const int k0_ = (c0 >> 3) & 3, k1_ = (c1 >> 3) & 3;
  const int fk0 = k0_ ^ ((k0_ & 1) << 2), fk1 = k1_ ^ ((k1_ & 1) << 2);
  const size_t off0 = (size_t)c0 * NPOS + (((lane & 7) ^ fk0) << 2);
  const size_t off1 = (size_t)c1 * NPOS + (((lane & 7) ^ fk1) << 2);

#define ISSUE(BUF, NC)                                                        \
  {                                                                           \
    __builtin_amdgcn_global_load_lds((guint*)(xb + off0 + (NC)),              \
        (luint*)&xf[BUF][wave * 16][0], 16, 0, 0);                            \
    __builtin_amdgcn_global_load_lds((guint*)(xb + off1 + (NC)),              \
        (luint*)&xf[BUF][wave * 16 + 8][0], 16, 0, 0);                        \
    __builtin_amdgcn_global_load_lds((guint*)(ib + off0 + (NC)),              \
        (luint*)&ifl[BUF][wave * 16][0], 16, 0, 0);                           \
    __builtin_amdgcn_global_load_lds((guint*)(ib + off1 + (NC)),              \
        (luint*)&ifl[BUF][wave * 16 + 8][0], 16, 0, 0);                       \
  }

  ISSUE(0, n0);
  BAR_VM0();

  const int fkr = g ^ ((g & 1) << 2);
  float tok = 0.f;

  for (int cc = 0; cc < 8; ++cc) {
    const int cb = cc & 1;
    const int nbase = n0 + cc * 32;
    if (cc < 7) ISSUE(cb ^ 1, nbase + 32);
    BAR_VM4();

    if constexpr (MODE == 1) {
      // staging skeleton only: one b32 consume per array per chunk
      tok += xf[cb][lane][0] + ifl[cb][lane][0];
    } else {
#pragma unroll 2
      for (int sub = 0; sub < 2; ++sub) {
        const int j0 = sub * 16;
        const int j = j0 + r;
        const int qw = ((((j >> 2) ^ fkr) << 2) | (j & 3));
        bfrag xB[2], iB[2];
#pragma unroll
        for (int s = 0; s < 2; ++s) {
          float xw[8], iw[8];
#pragma unroll
          for (int e = 0; e < 8; ++e) {
            const int c = s * 32 + g * 8 + e;
            xw[e] = xf[cb][c][qw];
            iw[e] = ifl[cb][c][qw];
          }
          bfrag fx, fi;
#pragma unroll
          for (int e = 0; e < 8; ++e) { fx[e] = (__bf16)xw[e]; fi[e] = (__bf16)iw[e]; }
          xB[s] = fx; iB[s] = fi;
        }
        facc av[4] = {}, gv[4] = {};
        __builtin_amdgcn_s_setprio(1);
#pragma unroll
        for (int ti = 0; ti < 4; ++ti) {
#pragma unroll
          for (int s = 0; s < 2; ++s) {
            av[ti] = __builtin_amdgcn_mfma_f32_16x16x32_bf16(wvA[ti][s], xB[s], av[ti], 0, 0, 0);
            gv[ti] = __builtin_amdgcn_mfma_f32_16x16x32_bf16(wlA[ti][s], iB[s], gv[ti], 0, 0, 0);
          }
        }
        __builtin_amdgcn_s_setprio(0);
        unsigned long long pks[4];
#pragma unroll
        for (int ti = 0; ti < 4; ++ti) {
          const float v0 = av[ti][0] * gv[ti][0], v1 = av[ti][1] * gv[ti][1];
          const float v2 = av[ti][2] * gv[ti][2], v3 = av[ti][3] * gv[ti][3];
          pks[ti] =
              (unsigned long long)((unsigned int)f2bu(v0) | ((unsigned int)f2bu(v1) << 16)) |
              ((unsigned long long)((unsigned int)f2bu(v2) | ((unsigned int)f2bu(v3) << 16)) << 32);
        }
        if constexpr (MODE == 2) {
#pragma unroll
          for (int ti = 0; ti < 4; ++ti) {
            KEEP((unsigned int)pks[ti]);
            KEEP((unsigned int)(pks[ti] >> 32));
          }
        } else {
#pragma unroll
          for (int ti = 0; ti < 4; ++ti) {
            const int i = wave * 64 + ti * 16 + g * 4;
            const int sw = (r & 7) << 4;
            *(unsigned long long*)(lvs[sub] + r * 512 + ((i * 2) ^ sw)) = pks[ti];
          }
          BAR_LGKM();
          // PV split into two independent chains
          facc ov0 = {0.f, 0.f, 0.f, 0.f}, ov1 = {0.f, 0.f, 0.f, 0.f};
          __builtin_amdgcn_s_setprio(1);
#pragma unroll
          for (int s8 = 0; s8 < 4; ++s8) {
            const int byte = (s8 * 64 + g * 16) ^ ((r & 7) << 4);
            bfrag vB = *(const bfrag*)(lvs[sub] + r * 512 + byte);
            ov0 = __builtin_amdgcn_mfma_f32_16x16x32_bf16(mtA[s8], vB, ov0, 0, 0, 0);
          }
#pragma unroll
          for (int s8 = 4; s8 < 8; ++s8) {
            const int byte = (s8 * 64 + g * 16) ^ ((r & 7) << 4);
            bfrag vB = *(const bfrag*)(lvs[sub] + r * 512 + byte);
            ov1 = __builtin_amdgcn_mfma_f32_16x16x32_bf16(mtA[s8], vB, ov1, 0, 0, 0);
          }
          __builtin_amdgcn_s_setprio(0);
#pragma unroll
          for (int q = 0; q < 4; ++q) {
            const float o = ov0[q] + ov1[q] + bcol[q];
            if constexpr (MODE == 3) {
              KEEP(o);
            } else {
              ob[(size_t)(wave * 16 + g * 4 + q) * NPOS + nbase + j0 + r] = o;
            }
          }
        }
      }
    }
  }
#undef ISSUE

  if constexpr (MODE != 0) {
    // keep lvs allocated in modes that don't use it (equal LDS across modes)
    if (threadIdx.x == 0) *(float*)lvs[0] = tok;
    KEEP(tok);
    if (threadIdx.x == 0) tokbuf[blockIdx.y * gridDim.x + blockIdx.x] = tok;
  }
}

extern "C" void kernel_launch(void* const* d_in, const int* in_sizes, int n_in,
                              void* d_out, int out_size, void* d_ws, size_t ws_size,
                              hipStream_t stream) {
  (void)in_sizes; (void)n_in; (void)out_size; (void)ws_size;
  const float* x    = (const float*)d_in[0];
  const float* illu = (const float*)d_in[1];
  const float* Wq   = (const float*)d_in[2];
  const float* Wk   = (const float*)d_in[3];
  const float* Wv   = (const float*)d_in[4];
  const float* WL   = (const float*)d_in[5];
  const float* rsc  = (const float*)d_in[6];
  const float* Wp   = (const float*)d_in[7];
  const float* bp   = (const float*)d_in[8];
  float* out = (float*)d_out;

  float* xxws = (float*)d_ws;                                        // 64 KB
  unsigned short* Mt  = (unsigned short*)((char*)d_ws + 65536);      // 128 KB
  unsigned short* WvT = (unsigned short*)((char*)d_ws + 65536 + 131072); // 32 KB
  unsigned short* WLT = WvT + INNER * CH;                            // 32 KB

  hipMemsetAsync(d_ws, 0, (size_t)4 * 4096 * sizeof(float), stream);
  hipLaunchKernelGGL(k0_wt, dim3(64), dim3(256), 0, stream, Wv, WL, WvT, WLT);
  hipLaunchKernelGGL(k1_xx, dim3(32, 4), dim3(256), 0, stream, x, xxws);
  hipLaunchKernelGGL(k2_attn, dim3(16), dim3(256), 0, stream, xxws, Wq, Wk, rsc, Wp, Mt);
  // real kernel first, then diagnostics (tokens overwrite consumed xx region)
  hipLaunchKernelGGL(k3t<0>, dim3(256, 4), dim3(256), 0, stream, x, illu, WvT, WLT, Mt, bp, out, xxws);
  hipLaunchKernelGGL(k3t<1>, dim3(256, 4), dim3(256), 0, stream, x, illu, WvT, WLT, Mt, bp, out, xxws);
  hipLaunchKernelGGL(k3t<2>, dim3(256, 4), dim3(256), 0, stream, x, illu, WvT, WLT, Mt, bp, out, xxws);
  hipLaunchKernelGGL(k3t<3>, dim3(256, 4), dim3(256), 0, stream, x, illu, WvT, WLT, Mt, bp, out, xxws);
}

// Round 12
// 173.105 us; speedup vs baseline: 1.0330x; 1.0330x over previous
//
#include <hip/hip_runtime.h>
#include <hip/hip_bf16.h>

// IG-MSA (transposed channel attention), restructured:
//   K0: WvT/WLT = bf16 transposes of Wv/WL ([i=256][c=64]) for fragment loads
//   K1: XX[b] = x[b] @ x[b]^T   (64x64 Gram of channels over n=65536)
//   K2: (MFMA) finalize attention, fold Wp -> Mt[b, c', i] bf16
//   K3: out[b,c,n] = M^T @ ((Wv^T x) * (WL^T illu)) + bp
//       round 12: in-register vgen->PV chain per wave (mfma32 C-layout feeds
//       mfma16 A-operand directly, HW-verified in round 7); cross-wave f32
//       partial-out reduction via tiny contiguous LDS exchange. No v tile.

#define NPOS 65536
#define CH 64
#define INNER 256

typedef __attribute__((ext_vector_type(8))) __bf16 bfrag;
typedef __attribute__((ext_vector_type(4))) float facc;
typedef __attribute__((ext_vector_type(4))) float fvec4;
typedef __attribute__((ext_vector_type(4))) short sh4;

typedef const __attribute__((address_space(1))) unsigned int guint;
typedef __attribute__((address_space(3))) unsigned int luint;

__device__ __forceinline__ unsigned short f2bu(float f) {
  return __builtin_bit_cast(unsigned short, (__bf16)f);
}

#if __has_builtin(__builtin_amdgcn_mfma_f32_16x16x16bf16_1k)
__device__ __forceinline__ facc mfma16(sh4 a, sh4 b, facc c) {
  return __builtin_amdgcn_mfma_f32_16x16x16bf16_1k(a, b, c, 0, 0, 0);
}
#else
__device__ __forceinline__ facc mfma16(sh4 a, sh4 b, facc c) {
  asm("v_mfma_f32_16x16x16_bf16 %0, %1, %2, %0" : "+v"(c) : "v"(a), "v"(b));
  return c;
}
#endif

#define SWA(row, colbyte) ((row) * 128 + ((colbyte) ^ (((row) & 7) << 4)))

#define BAR_VM4()  asm volatile("s_waitcnt vmcnt(4)\n\ts_barrier" ::: "memory")
#define BAR_VM0()  asm volatile("s_waitcnt vmcnt(0)\n\ts_barrier" ::: "memory")
#define BAR_LGKM() asm volatile("s_waitcnt lgkmcnt(0)\n\ts_barrier" ::: "memory")

// ---------------- K0: weight transpose to bf16 ----------------
__global__ __launch_bounds__(256) void k0_wt(const float* __restrict__ Wv,
                                             const float* __restrict__ WL,
                                             unsigned short* __restrict__ WvT,
                                             unsigned short* __restrict__ WLT) {
  int t = blockIdx.x * 256 + threadIdx.x;
  int c = t >> 8, i = t & 255;
  WvT[i * CH + c] = f2bu(Wv[c * INNER + i]);
  WLT[i * CH + c] = f2bu(WL[c * INNER + i]);
}

// ---------------- K1: channel Gram matrix ----------------
__global__ __launch_bounds__(256) void k1_xx(const float* __restrict__ x,
                                             float* __restrict__ xx) {
  const int b = blockIdx.y;
  const int wave = threadIdx.x >> 6, lane = threadIdx.x & 63;
  const int r = lane & 15, g = lane >> 4;
  const int gw = blockIdx.x * 4 + wave;
  const int per = NPOS / 128;
  const size_t n0 = (size_t)gw * per;
  const float* xb = x + (size_t)b * CH * NPOS;

  facc acc[4][4] = {};

  for (int n = 0; n < per; n += 32) {
    bfrag fr[4];
#pragma unroll
    for (int t = 0; t < 4; ++t) {
      const float* p = xb + (size_t)(16 * t + r) * NPOS + n0 + n + g * 8;
      fvec4 lo = *(const fvec4*)p;
      fvec4 hi = *(const fvec4*)(p + 4);
      bfrag f;
#pragma unroll
      for (int e = 0; e < 4; ++e) { f[e] = (__bf16)lo[e]; f[e + 4] = (__bf16)hi[e]; }
      fr[t] = f;
    }
#pragma unroll
    for (int ti = 0; ti < 4; ++ti)
#pragma unroll
      for (int tj = 0; tj < 4; ++tj)
        acc[ti][tj] = __builtin_amdgcn_mfma_f32_16x16x32_bf16(fr[ti], fr[tj],
                                                              acc[ti][tj], 0, 0, 0);
  }

  __shared__ float red[4][4096];
  float* my = red[wave];
#pragma unroll
  for (int ti = 0; ti < 4; ++ti)
#pragma unroll
    for (int tj = 0; tj < 4; ++tj)
#pragma unroll
      for (int q = 0; q < 4; ++q)
        my[(16 * ti + g * 4 + q) * 64 + 16 * tj + r] = acc[ti][tj][q];
  __syncthreads();
  float* xxb = xx + (size_t)b * 4096;
  for (int i = threadIdx.x; i < 4096; i += 256)
    atomicAdd(xxb + i, red[0][i] + red[1][i] + red[2][i] + red[3][i]);
}

// ---------------- K2: MFMA finalize attention, fold Wp ----------------
__global__ __launch_bounds__(256) void k2_attn(
    const float* __restrict__ xx, const float* __restrict__ Wq,
    const float* __restrict__ Wk, const float* __restrict__ rescale,
    const float* __restrict__ Wp, unsigned short* __restrict__ Mt) {
  const int b = blockIdx.x >> 2, h = blockIdx.x & 3;
  const int t = threadIdx.x;
  const int wave = t >> 6, lane = t & 63;
  const int r = lane & 15, g = lane >> 4;

  __shared__ __align__(16) char tXX[8192];
  __shared__ __align__(16) char tWq[8192];
  __shared__ __align__(16) char tWk[8192];
  __shared__ __align__(16) char tWp[8192];
  __shared__ __align__(16) char tZq[8192];
  __shared__ __align__(16) char tZk[8192];
  __shared__ __align__(16) char tAt[8192];
  __shared__ float gG[64][68];
  __shared__ float sMx[64][4], sSm[64][4];
  __shared__ float sNq[64], sNk[64];

  const float* xxb = xx + (size_t)b * 4096;
#pragma unroll
  for (int rep = 0; rep < 16; ++rep) {
    int idx = rep * 256 + t;
    int row = idx >> 6, col = idx & 63;
    *(unsigned short*)(tXX + SWA(row, col * 2)) = f2bu(xxb[idx]);
    float vq = Wq[row * INNER + h * 64 + col];
    float vk = Wk[row * INNER + h * 64 + col];
    *(unsigned short*)(tWq + SWA(col, row * 2)) = f2bu(vq);
    *(unsigned short*)(tWk + SWA(col, row * 2)) = f2bu(vk);
    *(unsigned short*)(tWp + SWA(col, row * 2)) = f2bu(Wp[(h * 64 + row) * CH + col]);
  }
  __syncthreads();

  facc zq[4] = {}, zk[4] = {};
#pragma unroll
  for (int s = 0; s < 2; ++s) {
    bfrag aq = *(const bfrag*)(tWq + SWA(16 * wave + r, s * 64 + g * 16));
    bfrag ak = *(const bfrag*)(tWk + SWA(16 * wave + r, s * 64 + g * 16));
#pragma unroll
    for (int tj = 0; tj < 4; ++tj) {
      bfrag bx = *(const bfrag*)(tXX + SWA(16 * tj + r, s * 64 + g * 16));
      zq[tj] = __builtin_amdgcn_mfma_f32_16x16x32_bf16(aq, bx, zq[tj], 0, 0, 0);
      zk[tj] = __builtin_amdgcn_mfma_f32_16x16x32_bf16(ak, bx, zk[tj], 0, 0, 0);
    }
  }
#pragma unroll
  for (int tj = 0; tj < 4; ++tj)
#pragma unroll
    for (int q = 0; q < 4; ++q) {
      int row = 16 * wave + g * 4 + q, colb = (16 * tj + r) * 2;
      *(unsigned short*)(tZq + SWA(row, colb)) = f2bu(zq[tj][q]);
      *(unsigned short*)(tZk + SWA(row, colb)) = f2bu(zk[tj][q]);
    }
  __syncthreads();

  facc ga[4] = {}, q2[4] = {}, k2[4] = {};
#pragma unroll
  for (int s = 0; s < 2; ++s) {
    bfrag azk = *(const bfrag*)(tZk + SWA(16 * wave + r, s * 64 + g * 16));
    bfrag azq = *(const bfrag*)(tZq + SWA(16 * wave + r, s * 64 + g * 16));
#pragma unroll
    for (int tj = 0; tj < 4; ++tj) {
      bfrag bq = *(const bfrag*)(tWq + SWA(16 * tj + r, s * 64 + g * 16));
      bfrag bk = *(const bfrag*)(tWk + SWA(16 * tj + r, s * 64 + g * 16));
      ga[tj] = __builtin_amdgcn_mfma_f32_16x16x32_bf16(azk, bq, ga[tj], 0, 0, 0);
      q2[tj] = __builtin_amdgcn_mfma_f32_16x16x32_bf16(azq, bq, q2[tj], 0, 0, 0);
      k2[tj] = __builtin_amdgcn_mfma_f32_16x16x32_bf16(azk, bk, k2[tj], 0, 0, 0);
    }
  }
#pragma unroll
  for (int tj = 0; tj < 4; ++tj)
#pragma unroll
    for (int q = 0; q < 4; ++q) {
      int row = 16 * wave + g * 4 + q, col = 16 * tj + r;
      gG[row][col] = ga[tj][q];
      if (row == col) { sNq[row] = q2[tj][q]; sNk[row] = k2[tj][q]; }
    }
  __syncthreads();

  if (t < 64) {
    sNq[t] = 1.f / fmaxf(sqrtf(sNq[t]), 1e-12f);
    sNk[t] = rescale[h] / fmaxf(sqrtf(sNk[t]), 1e-12f);
  }
  __syncthreads();

  {
    const int d = t >> 2, p = t & 3;
    const float ik = sNk[d];
    float le[16];
    float mx = -1e30f;
#pragma unroll
    for (int j = 0; j < 16; ++j) {
      float v = gG[d][16 * p + j] * ik * sNq[16 * p + j];
      le[j] = v; mx = fmaxf(mx, v);
    }
    sMx[d][p] = mx;
    __syncthreads();
    mx = fmaxf(fmaxf(sMx[d][0], sMx[d][1]), fmaxf(sMx[d][2], sMx[d][3]));
    float sm = 0.f;
#pragma unroll
    for (int j = 0; j < 16; ++j) { le[j] = __expf(le[j] - mx); sm += le[j]; }
    sSm[d][p] = sm;
    __syncthreads();
    sm = sSm[d][0] + sSm[d][1] + sSm[d][2] + sSm[d][3];
    const float inv = 1.f / sm;
#pragma unroll
    for (int j = 0; j < 16; ++j) {
      int e = 16 * p + j;
      *(unsigned short*)(tAt + SWA(e, d * 2)) = f2bu(le[j] * inv);
    }
  }
  __syncthreads();

  facc m[4] = {};
#pragma unroll
  for (int s = 0; s < 2; ++s) {
    bfrag aa = *(const bfrag*)(tAt + SWA(16 * wave + r, s * 64 + g * 16));
#pragma unroll
    for (int tj = 0; tj < 4; ++tj) {
      bfrag bw = *(const bfrag*)(tWp + SWA(16 * tj + r, s * 64 + g * 16));
      m[tj] = __builtin_amdgcn_mfma_f32_16x16x32_bf16(aa, bw, m[tj], 0, 0, 0);
    }
  }
#pragma unroll
  for (int tj = 0; tj < 4; ++tj)
#pragma unroll
    for (int q = 0; q < 4; ++q) {
      int e = 16 * wave + g * 4 + q, c2 = 16 * tj + r;
      Mt[((size_t)(b * CH + c2)) * INNER + h * 64 + e] = f2bu(m[tj][q]);
    }
}

// ---------------- K3: gated V + folded projection, in-register PV ----------------
__global__ __launch_bounds__(256) void k3_out(
    const float* __restrict__ x, const float* __restrict__ illu,
    const unsigned short* __restrict__ WvT, const unsigned short* __restrict__ WLT,
    const unsigned short* __restrict__ Mt, const float* __restrict__ bp,
    float* __restrict__ out) {
  const int b = blockIdx.y;
  const int wave = threadIdx.x >> 6, lane = threadIdx.x & 63;
  const int r = lane & 15, g = lane >> 4;
  const int n0 = blockIdx.x * 256;          // gridDim.x == 256; 8 chunks of 32 n

  __shared__ __align__(16) float xf[2][64][32];   // 16 KB
  __shared__ __align__(16) float ifl[2][64][32];  // 16 KB
  __shared__ __align__(16) fvec4 red[4][4][64];   // 16 KB partial-out exchange

  // --- resident fragments ---
  bfrag wvA[4][2], wlA[4][2];
  sh4 mtB[4][4];   // B-frags of mfma16: Mt[c2=ct*16+r][i0=wave*64+ti*16+g*4 ..+3]
#pragma unroll
  for (int ti = 0; ti < 4; ++ti) {
    const int i = wave * 64 + ti * 16 + r;
#pragma unroll
    for (int s = 0; s < 2; ++s) {
      wvA[ti][s] = *(const bfrag*)(WvT + i * CH + s * 32 + g * 8);
      wlA[ti][s] = *(const bfrag*)(WLT + i * CH + s * 32 + g * 8);
    }
#pragma unroll
    for (int ct = 0; ct < 4; ++ct)
      mtB[ti][ct] = *(const sh4*)(Mt + ((size_t)(b * CH + ct * 16 + r)) * INNER +
                                  wave * 64 + ti * 16 + g * 4);
  }
  const float bias = bp[wave * 16 + r];

  const float* xb = x + (size_t)b * CH * NPOS;
  const float* ib = illu + (size_t)b * CH * NPOS;
  float* ob = out + (size_t)b * CH * NPOS;

  // DMA per-lane source offsets (round-10 verified)
  const int c0 = wave * 16 + (lane >> 3);
  const int c1 = c0 + 8;
  const int k0_ = (c0 >> 3) & 3, k1_ = (c1 >> 3) & 3;
  const int fk0 = k0_ ^ ((k0_ & 1) << 2), fk1 = k1_ ^ ((k1_ & 1) << 2);
  const size_t off0 = (size_t)c0 * NPOS + (((lane & 7) ^ fk0) << 2);
  const size_t off1 = (size_t)c1 * NPOS + (((lane & 7) ^ fk1) << 2);

#define ISSUE(BUF, NC)                                                        \
  {                                                                           \
    __builtin_amdgcn_global_load_lds((guint*)(xb + off0 + (NC)),              \
        (luint*)&xf[BUF][wave * 16][0], 16, 0, 0);                            \
    __builtin_amdgcn_global_load_lds((guint*)(xb + off1 + (NC)),              \
        (luint*)&xf[BUF][wave * 16 + 8][0], 16, 0, 0);                        \
    __builtin_amdgcn_global_load_lds((guint*)(ib + off0 + (NC)),              \
        (luint*)&ifl[BUF][wave * 16][0], 16, 0, 0);                           \
    __builtin_amdgcn_global_load_lds((guint*)(ib + off1 + (NC)),              \
        (luint*)&ifl[BUF][wave * 16 + 8][0], 16, 0, 0);                       \
  }

  ISSUE(0, n0);
  BAR_VM0();

  const int fkr = g ^ ((g & 1) << 2);

  for (int cc = 0; cc < 8; ++cc) {
    const int cb = cc & 1;
    const int nbase = n0 + cc * 32;
    if (cc < 7) ISSUE(cb ^ 1, nbase + 32);
    BAR_VM4();                          // buf cb's DMA landed, all waves

#pragma unroll 2
    for (int sub = 0; sub < 2; ++sub) {
      const int j0 = sub * 16;
      const int j = j0 + r;
      const int qw = ((((j >> 2) ^ fkr) << 2) | (j & 3));
      // ---- B-fragments from f32 LDS (round-10 verified) ----
      bfrag xB[2], iB[2];
#pragma unroll
      for (int s = 0; s < 2; ++s) {
        float xw[8], iw[8];
#pragma unroll
        for (int e = 0; e < 8; ++e) {
          const int c = s * 32 + g * 8 + e;
          xw[e] = xf[cb][c][qw];
          iw[e] = ifl[cb][c][qw];
        }
        bfrag fx, fi;
#pragma unroll
        for (int e = 0; e < 8; ++e) { fx[e] = (__bf16)xw[e]; fi[e] = (__bf16)iw[e]; }
        xB[s] = fx; iB[s] = fi;
      }
      // ---- fused vgen -> gate -> PV, all in registers ----
      facc pout[4] = {};
      __builtin_amdgcn_s_setprio(1);
#pragma unroll
      for (int ti = 0; ti < 4; ++ti) {
        facc av = {}, gv = {};
#pragma unroll
        for (int s = 0; s < 2; ++s) {
          av = __builtin_amdgcn_mfma_f32_16x16x32_bf16(wvA[ti][s], xB[s], av, 0, 0, 0);
          gv = __builtin_amdgcn_mfma_f32_16x16x32_bf16(wlA[ti][s], iB[s], gv, 0, 0, 0);
        }
        // lane holds v[i=wave*64+ti*16+g*4+e][j=r] == A-frag of mfma16
        sh4 a2;
#pragma unroll
        for (int e = 0; e < 4; ++e) a2[e] = (short)f2bu(av[e] * gv[e]);
#pragma unroll
        for (int ct = 0; ct < 4; ++ct)
          pout[ct] = mfma16(a2, mtB[ti][ct], pout[ct]);
      }
      __builtin_amdgcn_s_setprio(0);
      // ---- cross-wave partial-out reduction (contiguous f32x4, tiny) ----
#pragma unroll
      for (int d = 1; d < 4; ++d) {
        const int ct = (wave + d) & 3;
        red[ct][wave][lane] = pout[ct];
      }
      BAR_LGKM();
      fvec4 tot = pout[wave];
#pragma unroll
      for (int d = 1; d < 4; ++d) {
        const int w2 = (wave + d) & 3;
        fvec4 p = red[wave][w2][lane];
        tot += p;
      }
      // lane stores out[c=wave*16+r][n = nbase+j0+g*4 .. +3]
      fvec4 o;
#pragma unroll
      for (int q = 0; q < 4; ++q) o[q] = tot[q] + bias;
      *(fvec4*)(ob + (size_t)(wave * 16 + r) * NPOS + nbase + j0 + g * 4) = o;
      BAR_LGKM();                       // reads done before next sub's writes
    }
  }
#undef ISSUE
}

extern "C" void kernel_launch(void* const* d_in, const int* in_sizes, int n_in,
                              void* d_out, int out_size, void* d_ws, size_t ws_size,
                              hipStream_t stream) {
  (void)in_sizes; (void)n_in; (void)out_size; (void)ws_size;
  const float* x    = (const float*)d_in[0];
  const float* illu = (const float*)d_in[1];
  const float* Wq   = (const float*)d_in[2];
  const float* Wk   = (const float*)d_in[3];
  const float* Wv   = (const float*)d_in[4];
  const float* WL   = (const float*)d_in[5];
  const float* rsc  = (const float*)d_in[6];
  const float* Wp   = (const float*)d_in[7];
  const float* bp   = (const float*)d_in[8];
  float* out = (float*)d_out;

  float* xxws = (float*)d_ws;                                        // 64 KB
  unsigned short* Mt  = (unsigned short*)((char*)d_ws + 65536);      // 128 KB
  unsigned short* WvT = (unsigned short*)((char*)d_ws + 65536 + 131072); // 32 KB
  unsigned short* WLT = WvT + INNER * CH;                            // 32 KB

  hipMemsetAsync(d_ws, 0, (size_t)4 * 4096 * sizeof(float), stream);
  hipLaunchKernelGGL(k0_wt, dim3(64), dim3(256), 0, stream, Wv, WL, WvT, WLT);
  hipLaunchKernelGGL(k1_xx, dim3(32, 4), dim3(256), 0, stream, x, xxws);
  hipLaunchKernelGGL(k2_attn, dim3(16), dim3(256), 0, stream, xxws, Wq, Wk, rsc, Wp, Mt);
  hipLaunchKernelGGL(k3_out, dim3(256, 4), dim3(256), 0, stream, x, illu, WvT, WLT, Mt, bp, out);
}